// Round 15
// baseline (137.908 us; speedup 1.0000x reference)
//
#include <hip/hip_runtime.h>
#include <math.h>

// Problem constants (reference: N=16384, D=128, T=0.07)
#define NROWS 16384
#define DDIM  128
constexpr float TEMP = 0.07f;
// Pre-scale trick: x *= sqrt(log2(e)/T) so MFMA emits acc = S*<xi,xj> and
// row_lse = ln(sum exp2(acc)). Diagonal (sim_ii = 1 exactly) masked out of
// the fp8 path, added analytically (2^S) in finalize (R11/R14: absmax 0.0;
// off-diag is ~2.3% of rowsum so fp8 error is damped ~44x).
constexpr float S_EXP = 1.44269504088896f / TEMP;  // 20.6099291

typedef __attribute__((ext_vector_type(4))) float f32x4;
typedef __attribute__((ext_vector_type(2))) float f32x2;

// async 16B global -> LDS (lds dest = wave-uniform base + lane*16)
__device__ __forceinline__ void gload_lds16(const unsigned char* g, unsigned char* l) {
  __builtin_amdgcn_global_load_lds(
      (const __attribute__((address_space(1))) unsigned int*)g,
      (__attribute__((address_space(3))) unsigned int*)l, 16, 0, 0);
}

// Convert + pre-scale to fp8 e4m3 (OCP); zero accum/cnt.
__global__ void convert_k(const float* __restrict__ x, unsigned char* __restrict__ xb,
                          float* __restrict__ accum, int* __restrict__ cnt) {
  const float R = 4.53981419f;  // sqrt(S_EXP); |x*R| <= ~1.3, inside e4m3 range
  int i = (blockIdx.x * blockDim.x + threadIdx.x) * 4;
  float4 v = *(const float4*)(x + i);
  int p = __builtin_amdgcn_cvt_pk_fp8_f32(v.x * R, v.y * R, 0, false);
  p = __builtin_amdgcn_cvt_pk_fp8_f32(v.z * R, v.w * R, p, true);
  *(int*)(xb + i) = p;
  if (blockIdx.x == 0 && threadIdx.x == 0) { *accum = 0.f; *cnt = 0; }
}

// Triangular Gram in fp8, R14 single-barrier-per-tile loop. R15 changes:
// (1) grid 2048 (s = 0..15): s==0 -> d=0..4 (5 tiles), else d=4s+1..4s+4
//     (union 0..64 once per I). 8 blocks/CU sequential -> dispatcher can
//     rebalance; R14's grid of exactly 4/CU had zero refill granularity.
// (2) packed f32x2 accumulation for row/col sums (v_pk_add_f32-eligible)
//     -- halves the epilogue add cycles. Scalar path only for d==0 tile.
// Loop (1 barrier/tile, csbuf double-buffered):
//   B (panel[ti&1] staged + csbuf[(ti-1)&1] complete)
//   -> store colpart(ti-1) -> stage(ti+1) -> compute(ti) -> write csbuf[ti&1]
// LDS swizzle (1 B/elem): 16B chunk (col,kc16) at physical chunk
// col*8 + (kc16 ^ ((col>>1)&7)) -> coalesced staging + conflict-free reads
// (SQ_LDS_BANK_CONFLICT=0 measured). Zero contended atomics. R8 lesson:
// min-waves 4, never 8. 512 thr = 8 waves; wave w: rows h*32 (h=w>>1),
// cols chalf*64 (chalf=w&1).
__global__ __launch_bounds__(512, 4)
void gram_tri_k(const unsigned char* __restrict__ xb, float* __restrict__ rowpart,
                float* __restrict__ colpart) {
  __shared__ unsigned char panel[2][128 * DDIM];  // 2 x 16 KB
  __shared__ float csbuf[2][512];                 // 2 x 2 KB

  const int tid = threadIdx.x;
  const int w = tid >> 6, lane = tid & 63;
  const int l15 = lane & 15, q = lane >> 4;
  const int I = (int)(blockIdx.x >> 4), s = (int)(blockIdx.x & 15);
  const int rI = I * 128;
  const int h = w >> 1, chalf = w & 1;
  const int dstart = (s == 0) ? 0 : 4 * s + 1;
  const int ntiles = (s == 0) ? 5 : 4;
  const int sc8 = lane >> 3, sk8 = lane & 7;  // staging lane constants

  // A frags: 16x16x32 fp8 A[m=l15][k=q*8+j] -> 8 contiguous bytes/lane
  long af[2][4];
  {
    const unsigned char* gA = xb + (size_t)(rI + h * 32 + l15) * DDIM + q * 8;
#pragma unroll
    for (int rt = 0; rt < 2; ++rt)
#pragma unroll
      for (int kt = 0; kt < 4; ++kt)
        af[rt][kt] = *(const long*)(gA + rt * 16 * DDIM + kt * 32);
  }

  // stage tile 0 into panel[0]
  {
    const unsigned char* gJ = xb + (size_t)(((I + dstart) & 127) * 128) * DDIM;
#pragma unroll
    for (int rr = 0; rr < 2; ++rr) {
      const int col = (w * 2 + rr) * 8 + sc8;
      gload_lds16(gJ + (size_t)col * DDIM + (sk8 ^ ((col >> 1) & 7)) * 16,
                  &panel[0][(w * 2 + rr) * 1024]);
    }
  }

  f32x2 rs2[2][2];  // [rt][pair]; pair p covers r = 2p, 2p+1
#pragma unroll
  for (int rt = 0; rt < 2; ++rt)
#pragma unroll
    for (int p = 0; p < 2; ++p) rs2[rt][p] = (f32x2){0.f, 0.f};

  for (int ti = 0; ti < ntiles; ++ti) {
    const int d = dstart + ti;
    __syncthreads();  // B: panel[ti&1] staged; csbuf[(ti-1)&1] complete
    // deferred colpart store for tile ti-1 (overlaps stage/compute)
    if (ti > 0) {
      const int pd = d - 1;
      const float* cp = csbuf[(ti - 1) & 1];
      if (pd != 0 && pd != 64 && tid < 128)
        colpart[(size_t)(pd - 1) * NROWS + ((I + pd) & 127) * 128 + tid] =
            cp[tid] + cp[128 + tid] + cp[256 + tid] + cp[384 + tid];
    }
    // stage ti+1 into the OTHER panel (its readers = compute(ti-1), done pre-B)
    if (ti + 1 < ntiles) {
      const unsigned char* gJ =
          xb + (size_t)(((I + dstart + ti + 1) & 127) * 128) * DDIM;
      unsigned char* bn = panel[(ti + 1) & 1];
#pragma unroll
      for (int rr = 0; rr < 2; ++rr) {
        const int col = (w * 2 + rr) * 8 + sc8;
        gload_lds16(gJ + (size_t)col * DDIM + (sk8 ^ ((col >> 1) & 7)) * 16,
                    bn + (w * 2 + rr) * 1024);
      }
    }
    const unsigned char* L = panel[ti & 1];
    const bool dz = (d == 0);

    float cstile[4];
#pragma unroll
    for (int ct = 0; ct < 4; ++ct) {
      const int colb = chalf * 64 + ct * 16 + l15;
      const int swz = (colb >> 1) & 7;
      long bfr[4];
#pragma unroll
      for (int kt = 0; kt < 4; ++kt)
        bfr[kt] = *(const long*)&L[colb * DDIM +
                                   ((((kt << 1) + (q >> 1)) ^ swz) << 4) +
                                   ((q & 1) << 3)];
      f32x2 cs2 = {0.f, 0.f};
#pragma unroll
      for (int rt = 0; rt < 2; ++rt) {
        f32x4 a = {0.f, 0.f, 0.f, 0.f};
#pragma unroll
        for (int kt = 0; kt < 4; ++kt)
          a = __builtin_amdgcn_mfma_f32_16x16x32_fp8_fp8(af[rt][kt], bfr[kt], a, 0, 0, 0);
        // C/D layout (dtype-independent): col = l15, row = q*4 + r
        if (dz) {  // d==0 tile only: scalar path with diagonal mask
#pragma unroll
          for (int r = 0; r < 4; ++r) {
            float e = __builtin_amdgcn_exp2f(a[r]);
            if ((h * 32 + rt * 16 + q * 4 + r) == colb) e = 0.f;
            rs2[rt][r >> 1][r & 1] += e;
            cs2[r & 1] += e;
          }
        } else {  // packed path: pk-adds for rs and cs
#pragma unroll
          for (int p = 0; p < 2; ++p) {
            f32x2 e2 = {__builtin_amdgcn_exp2f(a[2 * p]),
                        __builtin_amdgcn_exp2f(a[2 * p + 1])};
            rs2[rt][p] += e2;
            cs2 += e2;
          }
        }
      }
      cstile[ct] = cs2[0] + cs2[1];
    }
    // col partial: reduce over q (wave's 32 rows), stash per-(h,chalf)
#pragma unroll
    for (int m = 16; m <= 32; m <<= 1)
#pragma unroll
      for (int ct = 0; ct < 4; ++ct)
        cstile[ct] += __shfl_xor(cstile[ct], m, 64);
    if (q == 0) {
#pragma unroll
      for (int ct = 0; ct < 4; ++ct)
        csbuf[ti & 1][h * 128 + chalf * 64 + ct * 16 + l15] = cstile[ct];
    }
    // NO second barrier -- next iteration's B publishes csbuf[ti&1]
  }

  __syncthreads();  // csbuf[(ntiles-1)&1] complete
  // colpart store for the last tile
  {
    const int pd = dstart + ntiles - 1;
    const float* cp = csbuf[(ntiles - 1) & 1];
    if (pd != 0 && pd != 64 && tid < 128)
      colpart[(size_t)(pd - 1) * NROWS + ((I + pd) & 127) * 128 + tid] =
          cp[tid] + cp[128 + tid] + cp[256 + tid] + cp[384 + tid];
  }

  // unpack packed accumulators, then reduce over the 16 cols (l15)...
  float rs[2][4];
#pragma unroll
  for (int rt = 0; rt < 2; ++rt)
#pragma unroll
    for (int r = 0; r < 4; ++r) rs[rt][r] = rs2[rt][r >> 1][r & 1];
#pragma unroll
  for (int m = 1; m <= 8; m <<= 1)
#pragma unroll
    for (int rt = 0; rt < 2; ++rt)
#pragma unroll
      for (int r = 0; r < 4; ++r)
        rs[rt][r] += __shfl_xor(rs[rt][r], m, 64);
  // ...combine chalf halves via csbuf[0]; chalf=0 is the unique writer.
  __syncthreads();  // tail colpart store done reading csbuf
  if (chalf == 1 && l15 == 0) {
#pragma unroll
    for (int rt = 0; rt < 2; ++rt)
#pragma unroll
      for (int r = 0; r < 4; ++r)
        csbuf[0][h * 32 + rt * 16 + q * 4 + r] = rs[rt][r];
  }
  __syncthreads();
  if (chalf == 0 && l15 == 0) {
#pragma unroll
    for (int rt = 0; rt < 2; ++rt)
#pragma unroll
      for (int r = 0; r < 4; ++r) {
        const int ro = h * 32 + rt * 16 + q * 4 + r;
        rowpart[(size_t)s * NROWS + rI + ro] = rs[rt][r] + csbuf[0][ro];
      }
  }
}

// 256 blocks x 64 threads, 1 row/thread (coalesced): sums 16 rowpart +
// 63 colpart slices, adds analytic diagonal 2^S, logs, wave-reduces.
__global__ void finalize_k(const float* __restrict__ rowpart, const float* __restrict__ colpart,
                           float* __restrict__ accum, int* __restrict__ cnt,
                           float* __restrict__ out) {
  const int tid = threadIdx.x;
  const size_t i = (size_t)blockIdx.x * 64 + tid;
  float v = __builtin_exp2f(S_EXP);  // exact diagonal term (rows unit-norm)
#pragma unroll
  for (int s2 = 0; s2 < 16; ++s2) v += rowpart[(size_t)s2 * NROWS + i];
#pragma unroll
  for (int d = 1; d < 64; ++d) v += colpart[(size_t)(d - 1) * NROWS + i];
  float sm = __logf(v);
#pragma unroll
  for (int m = 1; m < 64; m <<= 1) sm += __shfl_xor(sm, m, 64);
  if (tid == 0) {
    atomicAdd(accum, sm);
    __threadfence();
    int prev = atomicAdd(cnt, 1);
    if (prev == (int)gridDim.x - 1) {
      __threadfence();
      float a = __hip_atomic_load(accum, __ATOMIC_RELAXED, __HIP_MEMORY_SCOPE_AGENT);
      out[0] = a / (float)NROWS;
    }
  }
}

extern "C" void kernel_launch(void* const* d_in, const int* in_sizes, int n_in,
                              void* d_out, int out_size, void* d_ws, size_t ws_size,
                              hipStream_t stream) {
  const float* x = (const float*)d_in[0];
  float* out = (float*)d_out;
  // ws layout: xb 2 MB (fp8) | rowpart 16x64KB | colpart 63x64KB | accum,cnt
  unsigned char* xb = (unsigned char*)d_ws;
  float* rowpart = (float*)((char*)d_ws + (size_t)NROWS * DDIM);
  float* colpart = rowpart + (size_t)16 * NROWS;
  float* accum = colpart + (size_t)63 * NROWS;
  int* cnt = (int*)(accum + 1);

  convert_k<<<NROWS * DDIM / (256 * 4), 256, 0, stream>>>(x, xb, accum, cnt);
  gram_tri_k<<<128 * 16, 512, 0, stream>>>(xb, rowpart, colpart);
  finalize_k<<<NROWS / 64, 64, 0, stream>>>(rowpart, colpart, accum, cnt, out);
}

// Round 16
// 129.726 us; speedup vs baseline: 1.0631x; 1.0631x over previous
//
#include <hip/hip_runtime.h>
#include <math.h>

// Problem constants (reference: N=16384, D=128, T=0.07)
#define NROWS 16384
#define DDIM  128
constexpr float TEMP = 0.07f;
// Pre-scale trick: x *= sqrt(log2(e)/T) so MFMA emits acc = S*<xi,xj> and
// row_lse = ln(sum exp2(acc)). Diagonal (sim_ii = 1 exactly) masked out of
// the fp8 path, added analytically (2^S) in finalize (R11/R14: absmax 0.0;
// off-diag is ~2.3% of rowsum so fp8 error is damped ~44x).
constexpr float S_EXP = 1.44269504088896f / TEMP;  // 20.6099291

typedef __attribute__((ext_vector_type(4))) float f32x4;
typedef __attribute__((ext_vector_type(2))) float f32x2;

// Force the packed add the compiler refuses to emit (R15: f32x2 += was
// scalarized; VALU-busy time unchanged). Operands are 64-bit vreg pairs.
__device__ __forceinline__ f32x2 pk_add(f32x2 a, f32x2 b) {
  f32x2 d;
  asm("v_pk_add_f32 %0, %1, %2" : "=v"(d) : "v"(a), "v"(b));
  return d;
}

// async 16B global -> LDS (lds dest = wave-uniform base + lane*16)
__device__ __forceinline__ void gload_lds16(const unsigned char* g, unsigned char* l) {
  __builtin_amdgcn_global_load_lds(
      (const __attribute__((address_space(1))) unsigned int*)g,
      (__attribute__((address_space(3))) unsigned int*)l, 16, 0, 0);
}

// Convert + pre-scale to fp8 e4m3 (OCP); zero accum/cnt.
__global__ void convert_k(const float* __restrict__ x, unsigned char* __restrict__ xb,
                          float* __restrict__ accum, int* __restrict__ cnt) {
  const float R = 4.53981419f;  // sqrt(S_EXP); |x*R| <= ~1.3, inside e4m3 range
  int i = (blockIdx.x * blockDim.x + threadIdx.x) * 4;
  float4 v = *(const float4*)(x + i);
  int p = __builtin_amdgcn_cvt_pk_fp8_f32(v.x * R, v.y * R, 0, false);
  p = __builtin_amdgcn_cvt_pk_fp8_f32(v.z * R, v.w * R, p, true);
  *(int*)(xb + i) = p;
  if (blockIdx.x == 0 && threadIdx.x == 0) { *accum = 0.f; *cnt = 0; }
}

// Triangular Gram in fp8 — R14 structure VERBATIM (best gram: 49.5 us,
// conflicts 0; R15's grid-2048 split regressed: +1.6M conflicts, 2x cold
// prologues) + R16: packed v_pk_add_f32 accumulation (halves the 536M
// scalar accumulate-adds ~= 14 us of the ~21 us VALU pipe).
// Loop (1 barrier/tile, csbuf double-buffered):
//   B (panel[ti&1] staged + csbuf[(ti-1)&1] complete)
//   -> store colpart(ti-1) -> stage(ti+1) -> compute(ti) -> write csbuf[ti&1]
// Block (I,s): d-tiles s==0: d=0..8 else 8s+1..8s+8 (union 0..64 once per
// I; d=0 diag-masked, d=0/64 col-skip -- proven R5-R14). Zero contended
// atomics. LDS swizzle (1 B/elem): 16B chunk (col,kc16) at physical chunk
// col*8 + (kc16 ^ ((col>>1)&7)) -> coalesced staging + conflict-free reads.
// R8 lesson: min-waves 4, never 8. 512 thr = 8 waves; wave w: rows h*32
// (h=w>>1), cols chalf*64 (chalf=w&1).
__global__ __launch_bounds__(512, 4)
void gram_tri_k(const unsigned char* __restrict__ xb, float* __restrict__ rowpart,
                float* __restrict__ colpart) {
  __shared__ unsigned char panel[2][128 * DDIM];  // 2 x 16 KB
  __shared__ float csbuf[2][512];                 // 2 x 2 KB

  const int tid = threadIdx.x;
  const int w = tid >> 6, lane = tid & 63;
  const int l15 = lane & 15, q = lane >> 4;
  const int I = (int)(blockIdx.x >> 3), s = (int)(blockIdx.x & 7);
  const int rI = I * 128;
  const int h = w >> 1, chalf = w & 1;
  const int dstart = (s == 0) ? 0 : 8 * s + 1;
  const int ntiles = (s == 0) ? 9 : 8;
  const int sc8 = lane >> 3, sk8 = lane & 7;  // staging lane constants

  // A frags: 16x16x32 fp8 A[m=l15][k=q*8+j] -> 8 contiguous bytes/lane
  long af[2][4];
  {
    const unsigned char* gA = xb + (size_t)(rI + h * 32 + l15) * DDIM + q * 8;
#pragma unroll
    for (int rt = 0; rt < 2; ++rt)
#pragma unroll
      for (int kt = 0; kt < 4; ++kt)
        af[rt][kt] = *(const long*)(gA + rt * 16 * DDIM + kt * 32);
  }

  // stage tile 0 into panel[0]
  {
    const unsigned char* gJ = xb + (size_t)(((I + dstart) & 127) * 128) * DDIM;
#pragma unroll
    for (int rr = 0; rr < 2; ++rr) {
      const int col = (w * 2 + rr) * 8 + sc8;
      gload_lds16(gJ + (size_t)col * DDIM + (sk8 ^ ((col >> 1) & 7)) * 16,
                  &panel[0][(w * 2 + rr) * 1024]);
    }
  }

  f32x2 rs2[2][2];  // [rt][pair]; pair p covers r = 2p, 2p+1
#pragma unroll
  for (int rt = 0; rt < 2; ++rt)
#pragma unroll
    for (int p = 0; p < 2; ++p) rs2[rt][p] = (f32x2){0.f, 0.f};

  for (int ti = 0; ti < ntiles; ++ti) {
    const int d = dstart + ti;
    __syncthreads();  // B: panel[ti&1] staged; csbuf[(ti-1)&1] complete
    // deferred colpart store for tile ti-1 (overlaps stage/compute)
    if (ti > 0) {
      const int pd = d - 1;
      const float* cp = csbuf[(ti - 1) & 1];
      if (pd != 0 && pd != 64 && tid < 128)
        colpart[(size_t)(pd - 1) * NROWS + ((I + pd) & 127) * 128 + tid] =
            cp[tid] + cp[128 + tid] + cp[256 + tid] + cp[384 + tid];
    }
    // stage ti+1 into the OTHER panel (its readers = compute(ti-1), done pre-B)
    if (ti + 1 < ntiles) {
      const unsigned char* gJ =
          xb + (size_t)(((I + dstart + ti + 1) & 127) * 128) * DDIM;
      unsigned char* bn = panel[(ti + 1) & 1];
#pragma unroll
      for (int rr = 0; rr < 2; ++rr) {
        const int col = (w * 2 + rr) * 8 + sc8;
        gload_lds16(gJ + (size_t)col * DDIM + (sk8 ^ ((col >> 1) & 7)) * 16,
                    bn + (w * 2 + rr) * 1024);
      }
    }
    const unsigned char* L = panel[ti & 1];
    const bool dz = (d == 0);

    float cstile[4];
#pragma unroll
    for (int ct = 0; ct < 4; ++ct) {
      const int colb = chalf * 64 + ct * 16 + l15;
      const int swz = (colb >> 1) & 7;
      long bfr[4];
#pragma unroll
      for (int kt = 0; kt < 4; ++kt)
        bfr[kt] = *(const long*)&L[colb * DDIM +
                                   ((((kt << 1) + (q >> 1)) ^ swz) << 4) +
                                   ((q & 1) << 3)];
      f32x2 cs2 = {0.f, 0.f};
#pragma unroll
      for (int rt = 0; rt < 2; ++rt) {
        f32x4 a = {0.f, 0.f, 0.f, 0.f};
#pragma unroll
        for (int kt = 0; kt < 4; ++kt)
          a = __builtin_amdgcn_mfma_f32_16x16x32_fp8_fp8(af[rt][kt], bfr[kt], a, 0, 0, 0);
        // C/D layout (dtype-independent): col = l15, row = q*4 + r
        if (dz) {  // d==0 tile only: scalar path with diagonal mask
#pragma unroll
          for (int r = 0; r < 4; ++r) {
            float e = __builtin_amdgcn_exp2f(a[r]);
            if ((h * 32 + rt * 16 + q * 4 + r) == colb) e = 0.f;
            rs2[rt][r >> 1][r & 1] += e;
            cs2[r & 1] += e;
          }
        } else {  // hot path: forced v_pk_add_f32 for rs and cs
#pragma unroll
          for (int p = 0; p < 2; ++p) {
            f32x2 e2 = {__builtin_amdgcn_exp2f(a[2 * p]),
                        __builtin_amdgcn_exp2f(a[2 * p + 1])};
            rs2[rt][p] = pk_add(rs2[rt][p], e2);
            cs2 = pk_add(cs2, e2);
          }
        }
      }
      cstile[ct] = cs2[0] + cs2[1];
    }
    // col partial: reduce over q (wave's 32 rows), stash per-(h,chalf)
#pragma unroll
    for (int m = 16; m <= 32; m <<= 1)
#pragma unroll
      for (int ct = 0; ct < 4; ++ct)
        cstile[ct] += __shfl_xor(cstile[ct], m, 64);
    if (q == 0) {
#pragma unroll
      for (int ct = 0; ct < 4; ++ct)
        csbuf[ti & 1][h * 128 + chalf * 64 + ct * 16 + l15] = cstile[ct];
    }
    // NO second barrier -- next iteration's B publishes csbuf[ti&1]
  }

  __syncthreads();  // csbuf[(ntiles-1)&1] complete
  // colpart store for the last tile
  {
    const int pd = dstart + ntiles - 1;
    const float* cp = csbuf[(ntiles - 1) & 1];
    if (pd != 0 && pd != 64 && tid < 128)
      colpart[(size_t)(pd - 1) * NROWS + ((I + pd) & 127) * 128 + tid] =
          cp[tid] + cp[128 + tid] + cp[256 + tid] + cp[384 + tid];
  }

  // unpack packed accumulators, then reduce over the 16 cols (l15)...
  float rs[2][4];
#pragma unroll
  for (int rt = 0; rt < 2; ++rt)
#pragma unroll
    for (int r = 0; r < 4; ++r) rs[rt][r] = rs2[rt][r >> 1][r & 1];
#pragma unroll
  for (int m = 1; m <= 8; m <<= 1)
#pragma unroll
    for (int rt = 0; rt < 2; ++rt)
#pragma unroll
      for (int r = 0; r < 4; ++r)
        rs[rt][r] += __shfl_xor(rs[rt][r], m, 64);
  // ...combine chalf halves via csbuf[0]; chalf=0 is the unique writer.
  __syncthreads();  // tail colpart store done reading csbuf
  if (chalf == 1 && l15 == 0) {
#pragma unroll
    for (int rt = 0; rt < 2; ++rt)
#pragma unroll
      for (int r = 0; r < 4; ++r)
        csbuf[0][h * 32 + rt * 16 + q * 4 + r] = rs[rt][r];
  }
  __syncthreads();
  if (chalf == 0 && l15 == 0) {
#pragma unroll
    for (int rt = 0; rt < 2; ++rt)
#pragma unroll
      for (int r = 0; r < 4; ++r) {
        const int ro = h * 32 + rt * 16 + q * 4 + r;
        rowpart[(size_t)s * NROWS + rI + ro] = rs[rt][r] + csbuf[0][ro];
      }
  }
}

// 256 blocks x 64 threads, 1 row/thread (coalesced): sums 8 rowpart +
// 63 colpart slices, adds analytic diagonal 2^S, logs, wave-reduces.
__global__ void finalize_k(const float* __restrict__ rowpart, const float* __restrict__ colpart,
                           float* __restrict__ accum, int* __restrict__ cnt,
                           float* __restrict__ out) {
  const int tid = threadIdx.x;
  const size_t i = (size_t)blockIdx.x * 64 + tid;
  float v = __builtin_exp2f(S_EXP);  // exact diagonal term (rows unit-norm)
#pragma unroll
  for (int s2 = 0; s2 < 8; ++s2) v += rowpart[(size_t)s2 * NROWS + i];
#pragma unroll
  for (int d = 1; d < 64; ++d) v += colpart[(size_t)(d - 1) * NROWS + i];
  float sm = __logf(v);
#pragma unroll
  for (int m = 1; m < 64; m <<= 1) sm += __shfl_xor(sm, m, 64);
  if (tid == 0) {
    atomicAdd(accum, sm);
    __threadfence();
    int prev = atomicAdd(cnt, 1);
    if (prev == (int)gridDim.x - 1) {
      __threadfence();
      float a = __hip_atomic_load(accum, __ATOMIC_RELAXED, __HIP_MEMORY_SCOPE_AGENT);
      out[0] = a / (float)NROWS;
    }
  }
}

extern "C" void kernel_launch(void* const* d_in, const int* in_sizes, int n_in,
                              void* d_out, int out_size, void* d_ws, size_t ws_size,
                              hipStream_t stream) {
  const float* x = (const float*)d_in[0];
  float* out = (float*)d_out;
  // ws layout: xb 2 MB (fp8) | rowpart 8x64KB | colpart 63x64KB | accum,cnt
  unsigned char* xb = (unsigned char*)d_ws;
  float* rowpart = (float*)((char*)d_ws + (size_t)NROWS * DDIM);
  float* colpart = rowpart + (size_t)8 * NROWS;
  float* accum = colpart + (size_t)63 * NROWS;
  int* cnt = (int*)(accum + 1);

  convert_k<<<NROWS * DDIM / (256 * 4), 256, 0, stream>>>(x, xb, accum, cnt);
  gram_tri_k<<<128 * 8, 512, 0, stream>>>(xb, rowpart, colpart);
  finalize_k<<<NROWS / 64, 64, 0, stream>>>(rowpart, colpart, accum, cnt, out);
}